// Round 5
// baseline (139.879 us; speedup 1.0000x reference)
//
#include <hip/hip_runtime.h>
#include <hip/hip_fp16.h>
#include <math.h>

#define PATCH 41
#define PP 1681          // 41*41
#define NB 8
#define STRIDE 10
#define PAD 4
#define CROW 48          // c row stride in halfs (16B-aligned rows for float4 reads)
#define CBIN 1992        // c bin stride in halfs; %64==8 -> bins spread across bank groups
#define NTH 256          // 4 waves

__device__ __forceinline__ constexpr float tri16(int k) {
    float d = (float)k + 0.5f - 8.0f;
    float a = d < 0.0f ? -d : d;
    return (8.0f - a) * 0.125f;   // u[i]*u[j] == pk[i][j] bit-exactly
}

// block-wide sum over 256 threads (4 waves). All threads must call.
__device__ __forceinline__ float block_sum(float v, float* s_red, int t) {
    #pragma unroll
    for (int o = 32; o > 0; o >>= 1) v += __shfl_xor(v, o);
    if ((t & 63) == 0) s_red[t >> 6] = v;
    __syncthreads();
    float total = s_red[0] + s_red[1] + s_red[2] + s_red[3];
    __syncthreads();
    return total;
}

__global__ __launch_bounds__(NTH, 4) void sift_desc_kernel(
        const float* __restrict__ x,   // [N,1,41,41]
        const float* __restrict__ gk,  // unused: recomputed via exp2
        const float* __restrict__ pk,  // unused: recomputed exactly
        float* __restrict__ out)       // [N,128]
{
    const int patch = blockIdx.x;
    const int t = threadIdx.x;

    __shared__ __align__(16) __half s_x[PP + 7];        // patch in f16
    __shared__ __align__(16) __half s_c[NB * CBIN];     // dense contrib, bin-major
    __shared__ __align__(16) __half s_H[NB * PATCH * 4];// H[b][row][ox]
    __shared__ float s_red[4];

    // ---- P0: load patch (f32->f16) + zero contrib array ----
    const float* xp = x + (size_t)patch * PP;
    for (int p = t; p < PP; p += NTH) s_x[p] = __float2half(xp[p]);
    {
        float4 z4 = make_float4(0.f, 0.f, 0.f, 0.f);
        float4* cz = (float4*)s_c;
        for (int k = t; k < (NB * CBIN) / 8; k += NTH) cz[k] = z4;
    }
    __syncthreads();

    // ---- P1: per-pixel (once!): grad, mag*gk, octant-direct soft binning,
    //      scatter 2 f16 values into dense bin-major contrib. No selects. ----
    for (int p = t; p < PP; p += NTH) {
        int i = p / PATCH;
        int j = p - i * PATCH;
        float xl = __half2float(s_x[p - (j > 0)]);
        float xr = __half2float(s_x[p + (j < PATCH - 1)]);
        float xu = __half2float(s_x[p - (i > 0) * PATCH]);
        float xd = __half2float(s_x[p + (i < PATCH - 1) * PATCH]);
        float gxv = xr - xl;
        float gyv = xd - xu;
        float X = gxv + 1e-10f;

        float di = (float)(i - 20), dj = (float)(j - 20);
        float gkv = exp2f((di * di + dj * dj) * -8.582362e-4f); // exp(-d/1681)
        float mag = sqrtf(gxv * gxv + gyv * gyv + 1e-10f) * gkv;

        // first-octant atan scaled by 4/pi (coeffs folded); a4 in [0,1]
        float ax = fabsf(X), ay = fabsf(gyv);
        float mx = fmaxf(ax, ay), mn = fminf(ax, ay);
        float r = mn * __builtin_amdgcn_rcpf(fmaxf(mx, 1e-30f));
        float r2 = r * r;
        float a4 = fmaf(r2, -0.0149238f, 0.0670406f);
        a4 = fmaf(r2, a4, -0.1482457f);
        a4 = fmaf(r2, a4, 0.2464287f);
        a4 = fmaf(r2, a4, -0.4235106f);
        a4 = fmaf(r2, a4, 1.2732106f);
        a4 *= r;

        // octant code -> bin index + interp weights (verified all 8 octants)
        bool sw = ay > ax;
        bool xn = X < 0.0f;
        bool yn = gyv < 0.0f;
        int q = (xn ? 2 : 0) + ((sw != xn) ? 1 : 0);
        int b0 = yn ? 7 - q : q;
        int b1 = (b0 + 1) & 7;
        bool f = (sw != xn) != yn;
        float ma = a4 * mag;
        float mb = mag - ma;
        float v0 = f ? ma : mb;   // mass for bin b0  ( = (1-w1)*mag )
        float v1 = f ? mb : ma;   // mass for bin b1  ( = w1*mag )

        int base = i * CROW + j;
        s_c[b0 * CBIN + base] = __float2half(v0);
        s_c[b1 * CBIN + base] = __float2half(v1);
    }
    __syncthreads();

    // ---- P2: horizontal triangular pool per (row, bin): vector LDS reads,
    //      compile-time weights, 4 window accumulators ----
    for (int u = t; u < PATCH * NB; u += NTH) {
        int row = u >> 3;
        int b = u & 7;
        const float4* c4 = (const float4*)(s_c + b * CBIN + row * CROW);
        union { float4 f4[6]; __half2 h2[24]; } ub;
        #pragma unroll
        for (int k = 0; k < 6; ++k) ub.f4[k] = c4[k];
        float rv[48];
        #pragma unroll
        for (int k = 0; k < 24; ++k) {
            rv[2 * k]     = __low2float(ub.h2[k]);
            rv[2 * k + 1] = __high2float(ub.h2[k]);
        }
        float h0 = 0.f, h1 = 0.f, h2 = 0.f, h3 = 0.f;
        #pragma unroll
        for (int kx = 0; kx < 16; ++kx) {
            const float uw = tri16(kx);
            { int j = 0 * STRIDE - PAD + kx; if (j >= 0)        h0 = fmaf(uw, rv[j], h0); }
            { int j = 1 * STRIDE - PAD + kx;                    h1 = fmaf(uw, rv[j], h1); }
            { int j = 2 * STRIDE - PAD + kx;                    h2 = fmaf(uw, rv[j], h2); }
            { int j = 3 * STRIDE - PAD + kx; if (j <= PATCH - 1) h3 = fmaf(uw, rv[j], h3); }
        }
        union { __half2 hh[2]; float2 ff; } ob;
        ob.hh[0] = __floats2half2_rn(h0, h1);
        ob.hh[1] = __floats2half2_rn(h2, h3);
        *(float2*)&s_H[(b * PATCH + row) * 4] = ob.ff;
    }
    __syncthreads();

    // ---- P3: vertical triangular pool (128 active threads) ----
    float v = 0.0f;
    if (t < 128) {
        int b = t >> 4;
        int oy = (t >> 2) & 3;
        int ox = t & 3;
        int iy0 = oy * STRIDE - PAD;
        float acc = 0.0f;
        #pragma unroll
        for (int ky = 0; ky < 16; ++ky) {
            int iy = iy0 + ky;
            if ((unsigned)iy <= (unsigned)(PATCH - 1))
                acc = fmaf(tri16(ky), __half2float(s_H[(b * PATCH + iy) * 4 + ox]), acc);
        }
        v = acc;
    }

    // ---- P4: L2 -> clip 0.2 -> L2 -> L1 -> sqrt ----
    float sumsq = block_sum(v * v, s_red, t);
    v *= 1.0f / fmaxf(sqrtf(sumsq), 1e-12f);
    v = fminf(fmaxf(v, 0.0f), 0.2f);

    float sumsq2 = block_sum(v * v, s_red, t);
    v *= 1.0f / fmaxf(sqrtf(sumsq2), 1e-12f);

    float l1 = block_sum(v, s_red, t);   // v >= 0 after clip
    v = v / fmaxf(l1, 1e-12f);

    if (t < 128) out[(size_t)patch * 128 + t] = sqrtf(v + 1e-10f);
}

extern "C" void kernel_launch(void* const* d_in, const int* in_sizes, int n_in,
                              void* d_out, int out_size, void* d_ws, size_t ws_size,
                              hipStream_t stream) {
    const float* x  = (const float*)d_in[0];
    const float* gk = (const float*)d_in[1];
    const float* pk = (const float*)d_in[2];
    float* out = (float*)d_out;
    const int n = in_sizes[0] / PP;   // 8192 patches
    sift_desc_kernel<<<n, NTH, 0, stream>>>(x, gk, pk, out);
}

// Round 6
// 124.653 us; speedup vs baseline: 1.1221x; 1.1221x over previous
//
#include <hip/hip_runtime.h>
#include <hip/hip_fp16.h>
#include <math.h>

#define PATCH 41
#define PP 1681          // 41*41
#define NB 8
#define STRIDE 10
#define PAD 4
#define NTH 256          // 4 waves
#define CPIX (PP + 14)   // 4 front + 10 back headroom pixels (zeroed)

__device__ __forceinline__ constexpr float tri16(int k) {
    float d = (float)k + 0.5f - 8.0f;
    float a = d < 0.0f ? -d : d;
    return (8.0f - a) * 0.125f;   // u[i]*u[j] == pk[i][j] bit-exactly
}

// block-wide sum over 256 threads (4 waves). All threads must call.
__device__ __forceinline__ float block_sum(float v, float* s_red, int t) {
    #pragma unroll
    for (int o = 32; o > 0; o >>= 1) v += __shfl_xor(v, o);
    if ((t & 63) == 0) s_red[t >> 6] = v;
    __syncthreads();
    float total = s_red[0] + s_red[1] + s_red[2] + s_red[3];
    __syncthreads();
    return total;
}

__global__ __launch_bounds__(NTH, 5) void sift_desc_kernel(
        const float* __restrict__ x,   // [N,1,41,41]
        const float* __restrict__ gk,  // unused: recomputed via exp2
        const float* __restrict__ pk,  // unused: recomputed exactly
        float* __restrict__ out)       // [N,128]
{
    const int patch = blockIdx.x;
    const int t = threadIdx.x;

    // pixel-major packed contrib: 8 f16 bins = 16B per pixel
    __shared__ __align__(16) __half s_c[CPIX * NB];          // 27.1 KB
    __shared__ __align__(16) char s_xbuf[(PP + 7) * 2];      // 3.4 KB: x(f16), later H
    __shared__ float s_red[4];
    __half* s_x = (__half*)s_xbuf;           // live in P0/P1
    __half* s_H = (__half*)s_xbuf;           // live in P2/P3 (x is dead)

    // ---- P0: load patch (f32->f16); zero headroom pixels of s_c ----
    const float* xp = x + (size_t)patch * PP;
    for (int p = t; p < PP; p += NTH) s_x[p] = __float2half(xp[p]);
    if (t < 14) {
        uint4 z; z.x = z.y = z.z = z.w = 0u;
        int idx = (t < 4) ? t : (PP + t);    // front 0..3, back PP+4..PP+13
        *(uint4*)&s_c[idx * NB] = z;
    }
    __syncthreads();

    // ---- P1: per-pixel once: grad, mag*gk, octant-direct soft binning,
    //      pack 8 f16 bins into 4 dwords in registers, ONE ds_write_b128. ----
    for (int p = t; p < PP; p += NTH) {
        int i = p / PATCH;
        int j = p - i * PATCH;
        float xl = __half2float(s_x[p - (j > 0)]);
        float xr = __half2float(s_x[p + (j < PATCH - 1)]);
        float xu = __half2float(s_x[p - (i > 0) * PATCH]);
        float xd = __half2float(s_x[p + (i < PATCH - 1) * PATCH]);
        float gxv = xr - xl;
        float gyv = xd - xu;
        float X = gxv + 1e-10f;

        float di = (float)(i - 20), dj = (float)(j - 20);
        float gkv = __builtin_amdgcn_exp2f((di * di + dj * dj) * -8.582362e-4f);
        float mag = __builtin_amdgcn_sqrtf(fmaf(gxv, gxv, fmaf(gyv, gyv, 1e-10f))) * gkv;

        // first-octant atan scaled by 4/pi (coeffs folded); a4 in [0,1]
        float ax = fabsf(X), ay = fabsf(gyv);
        float mx = fmaxf(ax, ay), mn = fminf(ax, ay);
        float r = mn * __builtin_amdgcn_rcpf(fmaxf(mx, 1e-30f));
        float r2 = r * r;
        float a4 = fmaf(r2, -0.0149238f, 0.0670406f);
        a4 = fmaf(r2, a4, -0.1482457f);
        a4 = fmaf(r2, a4, 0.2464287f);
        a4 = fmaf(r2, a4, -0.4235106f);
        a4 = fmaf(r2, a4, 1.2732106f);
        a4 *= r;

        // octant code -> bin index + interp masses (verified all 8 octants, R5)
        bool sw = ay > ax;
        bool xn = X < 0.0f;
        bool yn = gyv < 0.0f;
        int q = (xn ? 2 : 0) + ((sw != xn) ? 1 : 0);
        int b0 = yn ? 7 - q : q;
        bool f = (sw != xn) != yn;
        float ma = a4 * mag;
        float mb = mag - ma;
        float v0 = f ? ma : mb;   // mass for bin b0   ( = (1-w1)*mag )
        float v1 = f ? mb : ma;   // mass for bin b0+1 ( = w1*mag )

        // pack: b0 even -> word rA = (v0|v1<<16), word rB = 0
        //       b0 odd  -> word rA = v0<<16, word rB ((rA+1)&3) = v1
        unsigned v0h = (unsigned)__half_as_ushort(__float2half(v0));
        unsigned v1h = (unsigned)__half_as_ushort(__float2half(v1));
        bool odd = (b0 & 1) != 0;
        unsigned wA = odd ? (v0h << 16) : (v0h | (v1h << 16));
        unsigned wB = odd ? v1h : 0u;
        int rA = b0 >> 1;
        int rB = (rA + 1) & 3;
        uint4 cw;
        cw.x = (rA == 0 ? wA : 0u) | (rB == 0 ? wB : 0u);
        cw.y = (rA == 1 ? wA : 0u) | (rB == 1 ? wB : 0u);
        cw.z = (rA == 2 ? wA : 0u) | (rB == 2 ? wB : 0u);
        cw.w = (rA == 3 ? wA : 0u) | (rB == 3 ? wB : 0u);
        *(uint4*)&s_c[(p + 4) * NB] = cw;
    }
    __syncthreads();

    // ---- P2: horizontal triangular pool, all 8 bins at once via v_pk_fma_f16.
    //      One thread per (row, ox): 16 x [ds_read_b128 + 4 hfma2]. ----
    if (t < PATCH * 4) {
        const int row = t >> 2;
        const int ox = t & 3;
        const int sbase = row * PATCH + ox * STRIDE;  // stored idx = logical + 4 headroom
        const __half2 z2 = __float2half2_rn(0.0f);
        __half2 a0 = z2, a1 = z2, a2 = z2, a3 = z2;
        #pragma unroll
        for (int kx = 0; kx < 16; ++kx) {
            const float w = tri16(kx);
            __half2 wp = __float2half2_rn(w);
            if (kx < PAD)  wp = (ox > 0) ? wp : z2;   // j<0 only for ox==0
            if (kx == 15)  wp = (ox < 3) ? wp : z2;   // j>40 only for ox==3
            uint4 cwv = *(const uint4*)&s_c[(sbase + kx) * NB];
            a0 = __hfma2(wp, *(__half2*)&cwv.x, a0);
            a1 = __hfma2(wp, *(__half2*)&cwv.y, a1);
            a2 = __hfma2(wp, *(__half2*)&cwv.z, a2);
            a3 = __hfma2(wp, *(__half2*)&cwv.w, a3);
        }
        uint4 hv;
        hv.x = *(unsigned*)&a0;
        hv.y = *(unsigned*)&a1;
        hv.z = *(unsigned*)&a2;
        hv.w = *(unsigned*)&a3;
        *(uint4*)&s_H[(row * 4 + ox) * NB] = hv;   // H[row][ox][8 bins f16]
    }
    __syncthreads();

    // ---- P3: vertical triangular pool, f32 accumulate (128 active) ----
    float v = 0.0f;
    if (t < 128) {
        int b = t >> 4;
        int oy = (t >> 2) & 3;
        int ox = t & 3;
        #pragma unroll
        for (int ky = 0; ky < 16; ++ky) {
            const float w = tri16(ky);
            int iy = oy * STRIDE - PAD + ky;
            int iyc = min(max(iy, 0), PATCH - 1);
            float hv = __half2float(s_H[(iyc * 4 + ox) * NB + b]);
            v = fmaf((iy == iyc) ? w : 0.0f, hv, v);
        }
    }

    // ---- P4: L2 -> clip 0.2 -> L2 -> L1 -> sqrt ----
    float sumsq = block_sum(v * v, s_red, t);
    v *= 1.0f / fmaxf(__builtin_amdgcn_sqrtf(sumsq), 1e-12f);
    v = fminf(fmaxf(v, 0.0f), 0.2f);

    float sumsq2 = block_sum(v * v, s_red, t);
    v *= 1.0f / fmaxf(__builtin_amdgcn_sqrtf(sumsq2), 1e-12f);

    float l1 = block_sum(v, s_red, t);   // v >= 0 after clip
    v = v / fmaxf(l1, 1e-12f);

    if (t < 128) out[(size_t)patch * 128 + t] = __builtin_amdgcn_sqrtf(v + 1e-10f);
}

extern "C" void kernel_launch(void* const* d_in, const int* in_sizes, int n_in,
                              void* d_out, int out_size, void* d_ws, size_t ws_size,
                              hipStream_t stream) {
    const float* x  = (const float*)d_in[0];
    const float* gk = (const float*)d_in[1];
    const float* pk = (const float*)d_in[2];
    float* out = (float*)d_out;
    const int n = in_sizes[0] / PP;   // 8192 patches
    sift_desc_kernel<<<n, NTH, 0, stream>>>(x, gk, pk, out);
}

// Round 7
// 123.346 us; speedup vs baseline: 1.1340x; 1.0106x over previous
//
#include <hip/hip_runtime.h>
#include <hip/hip_fp16.h>
#include <math.h>

#define PATCH 41
#define PP 1681          // 41*41
#define NB 8
#define STRIDE 10
#define PAD 4
#define NTH 256          // 4 waves
#define CPIX (PP + 14)   // 4 front + 10 back headroom pixels (zeroed)
#define XROW 44          // padded x row stride in halfs (col -1..42)
#define XSZ (PATCH * XROW)

__device__ __forceinline__ constexpr float tri16(int k) {
    float d = (float)k + 0.5f - 8.0f;
    float a = d < 0.0f ? -d : d;
    return (8.0f - a) * 0.125f;   // u[i]*u[j] == pk[i][j] bit-exactly
}

// 4 consecutive f16 -> f32, half-index k must be even
__device__ __forceinline__ void load4(const __half* s, int k,
                                      float& f0, float& f1, float& f2, float& f3) {
    __half2 lo = *(const __half2*)&s[k];
    __half2 hi = *(const __half2*)&s[k + 2];
    f0 = __low2float(lo);  f1 = __high2float(lo);
    f2 = __low2float(hi);  f3 = __high2float(hi);
}

// per-pixel: grad -> packed 8-bin f16 contrib word (16B)
__device__ __forceinline__ uint4 pixel_contrib(float gx, float gy, float gauss) {
    float X = gx + 1e-10f;
    float mag = __builtin_amdgcn_sqrtf(fmaf(gx, gx, fmaf(gy, gy, 1e-10f))) * gauss;

    float ax = fabsf(X), ay = fabsf(gy);
    float mx = fmaxf(ax, ay), mn = fminf(ax, ay);
    float r = mn * __builtin_amdgcn_rcpf(fmaxf(mx, 1e-30f));
    float r2 = r * r;
    float a4 = fmaf(r2, -0.0149238f, 0.0670406f);
    a4 = fmaf(r2, a4, -0.1482457f);
    a4 = fmaf(r2, a4, 0.2464287f);
    a4 = fmaf(r2, a4, -0.4235106f);
    a4 = fmaf(r2, a4, 1.2732106f);
    a4 *= r;

    bool sw = ay > ax;
    bool xn = X < 0.0f;
    bool yn = gy < 0.0f;
    int q = (xn ? 2 : 0) + ((sw != xn) ? 1 : 0);
    int b0 = yn ? 7 - q : q;              // bin for (1-w1) mass
    bool f = (sw != xn) != yn;
    float ma = a4 * mag;
    float mb = mag - ma;
    float v0 = f ? ma : mb;               // mass for bin b0
    float v1 = f ? mb : ma;               // mass for bin (b0+1)&7

    // pack v0,v1 into one dword, place at half-slot b0 in a 128-bit word
    unsigned combo = __builtin_bit_cast(unsigned, __builtin_amdgcn_cvt_pkrtz(v0, v1));
    int sh = (b0 & 3) << 4;
    unsigned long long A = (unsigned long long)combo << sh;
    unsigned long long B = ((b0 & 3) == 3) ? (unsigned long long)(combo >> 16) : 0ull;
    bool lohalf = b0 < 4;
    unsigned long long lo = lohalf ? A : B;
    unsigned long long hi = lohalf ? B : A;
    uint4 cw;
    cw.x = (unsigned)lo; cw.y = (unsigned)(lo >> 32);
    cw.z = (unsigned)hi; cw.w = (unsigned)(hi >> 32);
    return cw;
}

__global__ __launch_bounds__(NTH, 5) void sift_desc_kernel(
        const float* __restrict__ x,   // [N,1,41,41]
        const float* __restrict__ gk,  // unused: recomputed via exp2 table
        const float* __restrict__ pk,  // unused: recomputed exactly
        float* __restrict__ out)       // [N,128]
{
    const int patch = blockIdx.x;
    const int t = threadIdx.x;

    __shared__ __align__(16) __half s_c[CPIX * NB];     // 27.1 KB pixel-major contrib
    __shared__ __align__(16) __half s_xp[XSZ];          // 3.6 KB padded f16 x; later H
    __shared__ float s_rc[PATCH];                       // separable gauss 1D
    __half* s_H = s_xp;                                 // alias: x dead after P1
    float* s_desc = reinterpret_cast<float*>(s_c);      // alias: c dead after P2

    // ---- P0: gauss table, padded f16 patch, zero contrib headroom ----
    if (t < PATCH) {
        float d = (float)(t - 20);
        s_rc[t] = __builtin_amdgcn_exp2f(d * d * -8.582362e-4f);
    }
    const float* xp = x + (size_t)patch * PP;
    for (int idx = t; idx < XSZ; idx += NTH) {
        int i = idx / XROW;
        int jj = idx - i * XROW - 1;               // [-1, 42]
        int jc = min(max(jj, 0), PATCH - 1);
        s_xp[idx] = __float2half(xp[i * PATCH + jc]);
    }
    if (t < 14) {
        uint4 z; z.x = z.y = z.z = z.w = 0u;
        int idx = (t < 4) ? t : (PP + t);          // front 0..3, back PP+4..PP+13
        *(uint4*)&s_c[idx * NB] = z;
    }
    __syncthreads();

    // ---- P1: 21 col-pairs x 11 row-strips, 3-row register window.
    //      One new 8B row-segment load per 2 pixels. ----
    if (t < 231) {
        const int strip = t / 21;                  // 0..10
        const int pairc = t - strip * 21;          // 0..20
        const int j = 2 * pairc;                   // 0,2,...,40
        const int i0 = 4 * strip;
        const float cf0 = s_rc[j];
        const float cf1 = s_rc[min(j + 1, PATCH - 1)];
        const bool has1 = (j < PATCH - 1);         // pair 20's 2nd pixel is fake

        const int kMax = (PATCH - 1) * XROW + j;
        int kA = max(i0 - 1, 0) * XROW + j;
        int kB = i0 * XROW + j;
        float A0, A1, A2, A3, B0, B1, B2, B3;
        load4(s_xp, kA, A0, A1, A2, A3);
        load4(s_xp, kB, B0, B1, B2, B3);
        int kC = min(kB + XROW, kMax);
        int pbase = (i0 * PATCH + j + 4) * NB;     // half-index into s_c

        #pragma unroll
        for (int r = 0; r < 4; ++r) {
            const int i = i0 + r;
            const bool ok = (i < PATCH);
            float C0, C1, C2, C3;
            load4(s_xp, kC, C0, C1, C2, C3);
            float rf = s_rc[min(i, PATCH - 1)];

            uint4 cw0 = pixel_contrib(B2 - B0, C1 - A1, rf * cf0);
            uint4 cw1 = pixel_contrib(B3 - B1, C2 - A2, rf * cf1);
            if (ok) {
                *(uint4*)&s_c[pbase] = cw0;
                if (has1) *(uint4*)&s_c[pbase + NB] = cw1;
            }

            A0 = B0; A1 = B1; A2 = B2; A3 = B3;
            B0 = C0; B1 = C1; B2 = C2; B3 = C3;
            kC = min(kC + XROW, kMax);
            pbase += PATCH * NB;
        }
    }
    __syncthreads();

    // ---- P2: horizontal triangular pool, all 8 bins via v_pk_fma_f16 ----
    if (t < PATCH * 4) {
        const int row = t >> 2;
        const int ox = t & 3;
        const int sbase = row * PATCH + ox * STRIDE;  // stored idx = logical + 4
        const __half2 z2 = __float2half2_rn(0.0f);
        __half2 a0 = z2, a1 = z2, a2 = z2, a3 = z2;
        #pragma unroll
        for (int kx = 0; kx < 16; ++kx) {
            const float w = tri16(kx);
            __half2 wp = __float2half2_rn(w);
            if (kx < PAD)  wp = (ox > 0) ? wp : z2;   // j<0 only for ox==0
            if (kx == 15)  wp = (ox < 3) ? wp : z2;   // j>40 only for ox==3
            uint4 cwv = *(const uint4*)&s_c[(sbase + kx) * NB];
            a0 = __hfma2(wp, *(__half2*)&cwv.x, a0);
            a1 = __hfma2(wp, *(__half2*)&cwv.y, a1);
            a2 = __hfma2(wp, *(__half2*)&cwv.z, a2);
            a3 = __hfma2(wp, *(__half2*)&cwv.w, a3);
        }
        uint4 hv;
        hv.x = *(unsigned*)&a0;
        hv.y = *(unsigned*)&a1;
        hv.z = *(unsigned*)&a2;
        hv.w = *(unsigned*)&a3;
        *(uint4*)&s_H[(row * 4 + ox) * NB] = hv;   // H[row][ox][8 bins f16]
    }
    __syncthreads();

    // ---- P3: vertical triangular pool, f32 accumulate (128 active) ----
    float v = 0.0f;
    if (t < 128) {
        int b = t >> 4;
        int oy = (t >> 2) & 3;
        int ox = t & 3;
        #pragma unroll
        for (int ky = 0; ky < 16; ++ky) {
            const float w = tri16(ky);
            int iy = oy * STRIDE - PAD + ky;
            int iyc = min(max(iy, 0), PATCH - 1);
            float hv = __half2float(s_H[(iyc * 4 + ox) * NB + b]);
            v = fmaf((iy == iyc) ? w : 0.0f, hv, v);
        }
        s_desc[t] = v;
    }
    __syncthreads();

    // ---- P4: single-wave normalization chain + store ----
    if (t < 64) {
        float a = s_desc[t];
        float b = s_desc[t + 64];

        float ss = fmaf(a, a, b * b);
        #pragma unroll
        for (int o = 32; o > 0; o >>= 1) ss += __shfl_xor(ss, o);
        float inv = 1.0f / fmaxf(__builtin_amdgcn_sqrtf(ss), 1e-12f);
        a = fminf(fmaxf(a * inv, 0.0f), 0.2f);
        b = fminf(fmaxf(b * inv, 0.0f), 0.2f);

        float ss2 = fmaf(a, a, b * b);
        #pragma unroll
        for (int o = 32; o > 0; o >>= 1) ss2 += __shfl_xor(ss2, o);
        float inv2 = 1.0f / fmaxf(__builtin_amdgcn_sqrtf(ss2), 1e-12f);
        a *= inv2; b *= inv2;

        float l1 = a + b;                      // a,b >= 0 after clip
        #pragma unroll
        for (int o = 32; o > 0; o >>= 1) l1 += __shfl_xor(l1, o);
        float invl = 1.0f / fmaxf(l1, 1e-12f);

        float* op = out + (size_t)patch * 128;
        op[t]      = __builtin_amdgcn_sqrtf(fmaf(a, invl, 1e-10f));
        op[t + 64] = __builtin_amdgcn_sqrtf(fmaf(b, invl, 1e-10f));
    }
}

extern "C" void kernel_launch(void* const* d_in, const int* in_sizes, int n_in,
                              void* d_out, int out_size, void* d_ws, size_t ws_size,
                              hipStream_t stream) {
    const float* x  = (const float*)d_in[0];
    const float* gk = (const float*)d_in[1];
    const float* pk = (const float*)d_in[2];
    float* out = (float*)d_out;
    const int n = in_sizes[0] / PP;   // 8192 patches
    sift_desc_kernel<<<n, NTH, 0, stream>>>(x, gk, pk, out);
}